// Round 2
// baseline (214.301 us; speedup 1.0000x reference)
//
#include <hip/hip_runtime.h>
#include <hip/hip_bf16.h>
#include <math.h>

// Problem constants (from reference): N=10000, E=50000, D=32, H=4, DH=8
#define DD 32
#define HH 4
#define EDGE_BLOCKS 2048
#define NODE_BLOCKS 2048

__device__ __forceinline__ void atomicMaxFloat(float* addr, float val) {
    // sign-split trick; addr must be initialized to -inf
    if (val >= 0.0f) {
        atomicMax((int*)addr, __float_as_int(val));
    } else {
        atomicMin((unsigned int*)addr, __float_as_uint(val));
    }
}

// ---------------- Kernel A: per-edge linear + score -----------------
// Persistent grid-stride: 2048 blocks x 256 threads, each block walks edges
// e, e+2048, ... . Per iteration every thread issues ALL its loads up front
// (4x float4 weights + 2x float4 gathered features + biases + query) so
// ~12 loads/wave are in flight, and prefetches next iteration's src/dst
// indices before the compute so the gather dependency chain overlaps the
// weight stream.
__global__ __launch_bounds__(256) void edge_kernel(
    const float* __restrict__ in_feat,  // [N,32]
    const float* __restrict__ query,    // [N,32]
    const float* __restrict__ skw, const float* __restrict__ dkw,
    const float* __restrict__ skb, const float* __restrict__ dkb,
    const float* __restrict__ svw, const float* __restrict__ dvw,
    const float* __restrict__ svb, const float* __restrict__ dvb,
    const int* __restrict__ src, const int* __restrict__ dst,
    float* __restrict__ Kout,   // [E,32] (d_out chunk 1)
    float* __restrict__ Vout,   // [E,32] (d_out chunk 2)
    float* __restrict__ score,  // [E,4]  (workspace)
    int E)
{
    const int tid = threadIdx.x;
    const int r = tid >> 3;   // 0..31 : output row (= h*8+dh)
    const int t = tid & 7;    // 0..7  : column quarter

    int e = blockIdx.x;
    if (e >= E) return;
    int s = src[e];
    int d = dst[e];

    for (;;) {
        // ---- issue all loads for edge e ----
        const float4 u4 = *(const float4*)(in_feat + (size_t)s * DD + t * 4);
        const float4 v4 = *(const float4*)(in_feat + (size_t)d * DD + t * 4);

        const size_t woff = (size_t)e * 1024 + (size_t)r * 32 + (size_t)t * 4;
        const float4 a = *(const float4*)(skw + woff);
        const float4 b = *(const float4*)(dkw + woff);
        const float4 c = *(const float4*)(svw + woff);
        const float4 g = *(const float4*)(dvw + woff);

        const size_t bo = (size_t)e * DD + r;
        const float kb = skb[bo] + dkb[bo];          // broadcast within t-group
        const float vb = svb[bo] + dvb[bo];
        const float q  = query[(size_t)d * DD + r];  // broadcast within t-group

        // ---- prefetch next iteration's indices ----
        const int e_next = e + (int)gridDim.x;
        const bool more = (e_next < E);
        int s_next = 0, d_next = 0;
        if (more) { s_next = src[e_next]; d_next = dst[e_next]; }

        // ---- compute ----
        float pk = a.x * u4.x + a.y * u4.y + a.z * u4.z + a.w * u4.w
                 + b.x * v4.x + b.y * v4.y + b.z * v4.z + b.w * v4.w;
        float pv = c.x * u4.x + c.y * u4.y + c.z * u4.z + c.w * u4.w
                 + g.x * v4.x + g.y * v4.y + g.z * v4.z + g.w * v4.w;

        // reduce over the 8 column-lanes (t within a group); result on all 8
        #pragma unroll
        for (int m = 1; m <= 4; m <<= 1) {
            pk += __shfl_xor(pk, m);
            pv += __shfl_xor(pv, m);
        }

        const float kval = pk + kb;
        const float vval = pv + vb;
        if (t == 0) {
            Kout[bo] = kval;
            Vout[bo] = vval;
        }

        // head score: wave w holds rows 8w..8w+7 (head w); sum kval*q over
        // the 8 r-groups (masks 8/16/32 combine lanes with equal t)
        float prod = kval * q;
        #pragma unroll
        for (int m = 8; m <= 32; m <<= 1) prod += __shfl_xor(prod, m);
        if ((tid & 63) == 0) {
            score[(size_t)e * HH + (tid >> 6)] = prod;
        }

        if (!more) break;
        e = e_next; s = s_next; d = d_next;
    }
}

// ---------------- Kernel B1: init workspace ----------------
__global__ void init_kernel(float* __restrict__ smax, float* __restrict__ ssum,
                            float* __restrict__ agg, int NH, int ND)
{
    const int i = blockIdx.x * blockDim.x + threadIdx.x;
    if (i < NH) {
        smax[i] = __int_as_float(0xff800000);  // -inf
        ssum[i] = 0.0f;
    }
    if (i < ND) agg[i] = 0.0f;
}

// ---------------- Kernel B2: segment max ----------------
__global__ void smax_kernel(const float* __restrict__ score,
                            const int* __restrict__ dst,
                            float* __restrict__ smax, int EH)
{
    const int i = blockIdx.x * blockDim.x + threadIdx.x;
    if (i >= EH) return;
    const int e = i >> 2, h = i & 3;
    atomicMaxFloat(&smax[(size_t)dst[e] * HH + h], score[i]);
}

// ---------------- Kernel B3: exp + segment sum ----------------
__global__ void esum_kernel(const float* __restrict__ score,
                            const int* __restrict__ dst,
                            const float* __restrict__ smax,
                            float* __restrict__ ex, float* __restrict__ ssum,
                            int EH)
{
    const int i = blockIdx.x * blockDim.x + threadIdx.x;
    if (i >= EH) return;
    const int e = i >> 2, h = i & 3;
    const int d = dst[e];
    const float x = expf(score[i] - smax[(size_t)d * HH + h]);
    ex[i] = x;
    atomicAdd(&ssum[(size_t)d * HH + h], x);
}

// ---------------- Kernel B4: attn + weighted scatter-sum ----------------
__global__ void attn_agg_kernel(const float* __restrict__ ex,
                                const float* __restrict__ ssum,
                                const int* __restrict__ dst,
                                const float* __restrict__ V,     // [E,32]
                                float* __restrict__ attn_out,    // [E,4]
                                float* __restrict__ agg,         // [N,32]
                                int ED)
{
    const int i = blockIdx.x * blockDim.x + threadIdx.x;
    if (i >= ED) return;
    const int e = i >> 5, c = i & 31, h = c >> 3;
    const int d = dst[e];
    const float a = ex[(size_t)e * HH + h] / ssum[(size_t)d * HH + h];
    if ((c & 7) == 0) attn_out[(size_t)e * HH + h] = a;
    atomicAdd(&agg[(size_t)d * DD + c], V[i] * a);
}

// ---------------- Kernel C: node linear + relu + residual + LN ----------------
// Grid-stride persistent version (same rationale as edge_kernel).
__global__ __launch_bounds__(256) void node_kernel(
    const float* __restrict__ in_feat,  // [N,32]
    const float* __restrict__ node_w,   // [N,32,32]
    const float* __restrict__ node_b,   // [N,32]
    const float* __restrict__ agg,      // [N,32]
    const float* __restrict__ ln_g, const float* __restrict__ ln_b,
    float* __restrict__ out, int N)
{
    __shared__ float ys[DD];
    const int tid = threadIdx.x;
    const int r = tid >> 3, t = tid & 7;

    for (int n = blockIdx.x; n < N; n += gridDim.x) {
        const float4 a4 = *(const float4*)(agg + (size_t)n * DD + t * 4);
        const float4 w4 = *(const float4*)(node_w + (size_t)n * 1024 + (size_t)r * 32 + t * 4);
        const float nb = node_b[(size_t)n * DD + r];
        const float resid = in_feat[(size_t)n * DD + r];

        float p = w4.x * a4.x + w4.y * a4.y + w4.z * a4.z + w4.w * a4.w;
        #pragma unroll
        for (int m = 1; m <= 4; m <<= 1) p += __shfl_xor(p, m);
        if (t == 0) {
            ys[r] = fmaxf(p + nb, 0.0f) + resid;
        }
        __syncthreads();
        if (tid < 64) {
            const float y = (tid < DD) ? ys[tid] : 0.0f;
            float sum = y;
            #pragma unroll
            for (int m = 1; m <= 32; m <<= 1) sum += __shfl_xor(sum, m);
            const float mu = sum * (1.0f / DD);
            const float dy = (tid < DD) ? (y - mu) : 0.0f;
            float s2 = dy * dy;
            #pragma unroll
            for (int m = 1; m <= 32; m <<= 1) s2 += __shfl_xor(s2, m);
            const float var = s2 * (1.0f / DD);
            if (tid < DD) {
                out[(size_t)n * DD + tid] =
                    dy * rsqrtf(var + 1e-5f) * ln_g[tid] + ln_b[tid];
            }
        }
        __syncthreads();  // protect ys before next iteration's write
    }
}

extern "C" void kernel_launch(void* const* d_in, const int* in_sizes, int n_in,
                              void* d_out, int out_size, void* d_ws, size_t ws_size,
                              hipStream_t stream) {
    const float* in_feat = (const float*)d_in[0];
    const float* query   = (const float*)d_in[1];
    const float* skw     = (const float*)d_in[2];
    const float* dkw     = (const float*)d_in[3];
    const float* skb     = (const float*)d_in[4];
    const float* dkb     = (const float*)d_in[5];
    const float* svw     = (const float*)d_in[6];
    const float* dvw     = (const float*)d_in[7];
    const float* svb     = (const float*)d_in[8];
    const float* dvb     = (const float*)d_in[9];
    const float* node_w  = (const float*)d_in[10];
    const float* node_b  = (const float*)d_in[11];
    const float* ln_g    = (const float*)d_in[12];
    const float* ln_b    = (const float*)d_in[13];
    const int*   src     = (const int*)d_in[14];
    const int*   dst     = (const int*)d_in[15];

    const int N = in_sizes[0] / DD;     // 10000
    const int E = in_sizes[14];         // 50000
    const int NH = N * HH, ND = N * DD;
    const int EH = E * HH, ED = E * DD;

    // d_out layout (return order): out[N,32], K[E,32], V[E,32], attn[E,4]
    float* out_node = (float*)d_out;
    float* Kout     = out_node + (size_t)N * DD;
    float* Vout     = Kout + (size_t)E * DD;
    float* attn_out = Vout + (size_t)E * DD;

    // workspace: score[E*4] | ex[E*4] | smax[N*4] | ssum[N*4] | agg[N*32]
    float* ws    = (float*)d_ws;
    float* score = ws;
    float* ex    = score + EH;
    float* smax  = ex + EH;
    float* ssum  = smax + NH;
    float* agg   = ssum + NH;

    // A: per-edge linears + scores (dominant HBM stream)
    edge_kernel<<<EDGE_BLOCKS, 256, 0, stream>>>(in_feat, query, skw, dkw, skb, dkb,
                                                 svw, dvw, svb, dvb, src, dst,
                                                 Kout, Vout, score, E);
    // B1: init (must run every call — ws not re-poisoned between replays)
    init_kernel<<<(ND + 255) / 256, 256, 0, stream>>>(smax, ssum, agg, NH, ND);
    // B2: segment max
    smax_kernel<<<(EH + 255) / 256, 256, 0, stream>>>(score, dst, smax, EH);
    // B3: exp + segment sum
    esum_kernel<<<(EH + 255) / 256, 256, 0, stream>>>(score, dst, smax, ex, ssum, EH);
    // B4: attn + scatter-sum into agg
    attn_agg_kernel<<<(ED + 255) / 256, 256, 0, stream>>>(ex, ssum, dst, Vout,
                                                          attn_out, agg, ED);
    // C: per-node linear + relu + residual + LayerNorm
    node_kernel<<<NODE_BLOCKS, 256, 0, stream>>>(in_feat, node_w, node_b, agg,
                                                 ln_g, ln_b, out_node, N);
}

// Round 3
// 188.623 us; speedup vs baseline: 1.1361x; 1.1361x over previous
//
#include <hip/hip_runtime.h>
#include <hip/hip_bf16.h>
#include <math.h>

// Problem constants (from reference): N=10000, E=50000, D=32, H=4, DH=8
#define DD 32
#define HH 4

__device__ __forceinline__ void atomicMaxFloat(float* addr, float val) {
    // sign-split trick; addr must be initialized to -inf
    if (val >= 0.0f) {
        atomicMax((int*)addr, __float_as_int(val));
    } else {
        atomicMin((unsigned int*)addr, __float_as_uint(val));
    }
}

// ---------------- Kernel A: per-edge linear + score -----------------
// One block (256 threads) per TWO edges. tid = r*8 + t; r in [0,32) output
// row (h*8+dh), t in [0,8) column quarter. Each thread issues 12 independent
// weight float4 loads + 4 gathered feature float4s + biases/queries up
// front (launch_bounds(256,1) lifts the VGPR cap so they can all be in
// flight), then does both edges' FMAs + shuffle reductions.
__global__ __launch_bounds__(256, 1) void edge_kernel(
    const float* __restrict__ in_feat,  // [N,32]
    const float* __restrict__ query,    // [N,32]
    const float* __restrict__ skw, const float* __restrict__ dkw,
    const float* __restrict__ skb, const float* __restrict__ dkb,
    const float* __restrict__ svw, const float* __restrict__ dvw,
    const float* __restrict__ svb, const float* __restrict__ dvb,
    const int* __restrict__ src, const int* __restrict__ dst,
    float* __restrict__ Kout,   // [E,32] (d_out chunk 1)
    float* __restrict__ Vout,   // [E,32] (d_out chunk 2)
    float* __restrict__ score,  // [E,4]  (workspace)
    int E)
{
    const int tid = threadIdx.x;
    const int r = tid >> 3;   // 0..31
    const int t = tid & 7;    // 0..7

    const int e0 = blockIdx.x * 2;
    const int e1 = e0 + 1;
    if (e0 >= E) return;
    const bool has1 = (e1 < E);

    const int s0 = src[e0], d0 = dst[e0];
    const int s1 = has1 ? src[e1] : s0;
    const int d1 = has1 ? dst[e1] : d0;

    // ---- gathered features (L2/L3-resident, broadcast across r-groups) ----
    const float4 u0 = *(const float4*)(in_feat + (size_t)s0 * DD + t * 4);
    const float4 v0 = *(const float4*)(in_feat + (size_t)d0 * DD + t * 4);
    const float4 u1 = *(const float4*)(in_feat + (size_t)s1 * DD + t * 4);
    const float4 v1 = *(const float4*)(in_feat + (size_t)d1 * DD + t * 4);

    // ---- streamed per-edge weights: 12 independent float4 loads ----
    const size_t w0 = (size_t)e0 * 1024 + (size_t)r * 32 + (size_t)t * 4;
    const size_t w1 = w0 + 1024;
    const float4 a0 = *(const float4*)(skw + w0);
    const float4 b0 = *(const float4*)(dkw + w0);
    const float4 c0 = *(const float4*)(svw + w0);
    const float4 g0 = *(const float4*)(dvw + w0);
    const float4 a1 = *(const float4*)(skw + w1);
    const float4 b1 = *(const float4*)(dkw + w1);
    const float4 c1 = *(const float4*)(svw + w1);
    const float4 g1 = *(const float4*)(dvw + w1);

    // ---- biases + queries (small, L2-resident) ----
    const size_t bo0 = (size_t)e0 * DD + r;
    const size_t bo1 = bo0 + DD;
    const float kb0 = skb[bo0] + dkb[bo0];
    const float vb0 = svb[bo0] + dvb[bo0];
    const float kb1 = skb[bo1] + dkb[bo1];
    const float vb1 = svb[bo1] + dvb[bo1];
    const float q0 = query[(size_t)d0 * DD + r];
    const float q1 = query[(size_t)d1 * DD + r];

    // ---- compute edge 0 ----
    float pk0 = a0.x * u0.x + a0.y * u0.y + a0.z * u0.z + a0.w * u0.w
              + b0.x * v0.x + b0.y * v0.y + b0.z * v0.z + b0.w * v0.w;
    float pv0 = c0.x * u0.x + c0.y * u0.y + c0.z * u0.z + c0.w * u0.w
              + g0.x * v0.x + g0.y * v0.y + g0.z * v0.z + g0.w * v0.w;
    // ---- compute edge 1 ----
    float pk1 = a1.x * u1.x + a1.y * u1.y + a1.z * u1.z + a1.w * u1.w
              + b1.x * v1.x + b1.y * v1.y + b1.z * v1.z + b1.w * v1.w;
    float pv1 = c1.x * u1.x + c1.y * u1.y + c1.z * u1.z + c1.w * u1.w
              + g1.x * v1.x + g1.y * v1.y + g1.z * v1.z + g1.w * v1.w;

    // reduce over the 8 column-lanes (independent chains, interleaved)
    #pragma unroll
    for (int m = 1; m <= 4; m <<= 1) {
        pk0 += __shfl_xor(pk0, m);
        pv0 += __shfl_xor(pv0, m);
        pk1 += __shfl_xor(pk1, m);
        pv1 += __shfl_xor(pv1, m);
    }

    const float kval0 = pk0 + kb0, vval0 = pv0 + vb0;
    const float kval1 = pk1 + kb1, vval1 = pv1 + vb1;
    if (t == 0) {
        Kout[bo0] = kval0;
        Vout[bo0] = vval0;
        if (has1) { Kout[bo1] = kval1; Vout[bo1] = vval1; }
    }

    // head scores: wave w holds rows 8w..8w+7 (head w). masks 8/16/32
    // combine the 8 r-groups within the wave (lanes of equal t).
    float prod0 = kval0 * q0;
    float prod1 = kval1 * q1;
    #pragma unroll
    for (int m = 8; m <= 32; m <<= 1) {
        prod0 += __shfl_xor(prod0, m);
        prod1 += __shfl_xor(prod1, m);
    }
    if ((tid & 63) == 0) {
        const int h = tid >> 6;
        score[(size_t)e0 * HH + h] = prod0;
        if (has1) score[(size_t)e1 * HH + h] = prod1;
    }
}

// ---------------- Kernel B1: init workspace ----------------
__global__ void init_kernel(float* __restrict__ smax, float* __restrict__ ssum,
                            float* __restrict__ agg, int NH, int ND)
{
    const int i = blockIdx.x * blockDim.x + threadIdx.x;
    if (i < NH) {
        smax[i] = __int_as_float(0xff800000);  // -inf
        ssum[i] = 0.0f;
    }
    if (i < ND) agg[i] = 0.0f;
}

// ---------------- Kernel B2: segment max ----------------
__global__ void smax_kernel(const float* __restrict__ score,
                            const int* __restrict__ dst,
                            float* __restrict__ smax, int EH)
{
    const int i = blockIdx.x * blockDim.x + threadIdx.x;
    if (i >= EH) return;
    const int e = i >> 2, h = i & 3;
    atomicMaxFloat(&smax[(size_t)dst[e] * HH + h], score[i]);
}

// ---------------- Kernel B3: exp + segment sum ----------------
__global__ void esum_kernel(const float* __restrict__ score,
                            const int* __restrict__ dst,
                            const float* __restrict__ smax,
                            float* __restrict__ ex, float* __restrict__ ssum,
                            int EH)
{
    const int i = blockIdx.x * blockDim.x + threadIdx.x;
    if (i >= EH) return;
    const int e = i >> 2, h = i & 3;
    const int d = dst[e];
    const float x = expf(score[i] - smax[(size_t)d * HH + h]);
    ex[i] = x;
    atomicAdd(&ssum[(size_t)d * HH + h], x);
}

// ---------------- Kernel B4: attn + weighted scatter-sum ----------------
__global__ void attn_agg_kernel(const float* __restrict__ ex,
                                const float* __restrict__ ssum,
                                const int* __restrict__ dst,
                                const float* __restrict__ V,     // [E,32]
                                float* __restrict__ attn_out,    // [E,4]
                                float* __restrict__ agg,         // [N,32]
                                int ED)
{
    const int i = blockIdx.x * blockDim.x + threadIdx.x;
    if (i >= ED) return;
    const int e = i >> 5, c = i & 31, h = c >> 3;
    const int d = dst[e];
    const float a = ex[(size_t)e * HH + h] / ssum[(size_t)d * HH + h];
    if ((c & 7) == 0) attn_out[(size_t)e * HH + h] = a;
    atomicAdd(&agg[(size_t)d * DD + c], V[i] * a);
}

// ---------------- Kernel C: node linear + relu + residual + LN ----------------
__global__ __launch_bounds__(256) void node_kernel(
    const float* __restrict__ in_feat,  // [N,32]
    const float* __restrict__ node_w,   // [N,32,32]
    const float* __restrict__ node_b,   // [N,32]
    const float* __restrict__ agg,      // [N,32]
    const float* __restrict__ ln_g, const float* __restrict__ ln_b,
    float* __restrict__ out, int N)
{
    __shared__ float ys[DD];
    const int n = blockIdx.x;
    if (n >= N) return;
    const int tid = threadIdx.x;
    const int r = tid >> 3, t = tid & 7;

    const float4 a4 = *(const float4*)(agg + (size_t)n * DD + t * 4);
    const float4 w4 = *(const float4*)(node_w + (size_t)n * 1024 + (size_t)r * 32 + t * 4);
    float p = w4.x * a4.x + w4.y * a4.y + w4.z * a4.z + w4.w * a4.w;
    #pragma unroll
    for (int m = 1; m <= 4; m <<= 1) p += __shfl_xor(p, m);
    if (t == 0) {
        float y = p + node_b[(size_t)n * DD + r];
        y = fmaxf(y, 0.0f) + in_feat[(size_t)n * DD + r];
        ys[r] = y;
    }
    __syncthreads();
    if (tid < 64) {
        const float y = (tid < DD) ? ys[tid] : 0.0f;
        float sum = y;
        #pragma unroll
        for (int m = 1; m <= 32; m <<= 1) sum += __shfl_xor(sum, m);
        const float mu = sum * (1.0f / DD);
        const float dy = (tid < DD) ? (y - mu) : 0.0f;
        float s2 = dy * dy;
        #pragma unroll
        for (int m = 1; m <= 32; m <<= 1) s2 += __shfl_xor(s2, m);
        const float var = s2 * (1.0f / DD);
        if (tid < DD) {
            out[(size_t)n * DD + tid] =
                dy * rsqrtf(var + 1e-5f) * ln_g[tid] + ln_b[tid];
        }
    }
}

extern "C" void kernel_launch(void* const* d_in, const int* in_sizes, int n_in,
                              void* d_out, int out_size, void* d_ws, size_t ws_size,
                              hipStream_t stream) {
    const float* in_feat = (const float*)d_in[0];
    const float* query   = (const float*)d_in[1];
    const float* skw     = (const float*)d_in[2];
    const float* dkw     = (const float*)d_in[3];
    const float* skb     = (const float*)d_in[4];
    const float* dkb     = (const float*)d_in[5];
    const float* svw     = (const float*)d_in[6];
    const float* dvw     = (const float*)d_in[7];
    const float* svb     = (const float*)d_in[8];
    const float* dvb     = (const float*)d_in[9];
    const float* node_w  = (const float*)d_in[10];
    const float* node_b  = (const float*)d_in[11];
    const float* ln_g    = (const float*)d_in[12];
    const float* ln_b    = (const float*)d_in[13];
    const int*   src     = (const int*)d_in[14];
    const int*   dst     = (const int*)d_in[15];

    const int N = in_sizes[0] / DD;     // 10000
    const int E = in_sizes[14];         // 50000
    const int NH = N * HH, ND = N * DD;
    const int EH = E * HH, ED = E * DD;

    // d_out layout (return order): out[N,32], K[E,32], V[E,32], attn[E,4]
    float* out_node = (float*)d_out;
    float* Kout     = out_node + (size_t)N * DD;
    float* Vout     = Kout + (size_t)E * DD;
    float* attn_out = Vout + (size_t)E * DD;

    // workspace: score[E*4] | ex[E*4] | smax[N*4] | ssum[N*4] | agg[N*32]
    float* ws    = (float*)d_ws;
    float* score = ws;
    float* ex    = score + EH;
    float* smax  = ex + EH;
    float* ssum  = smax + NH;
    float* agg   = ssum + NH;

    // A: per-edge linears + scores (dominant HBM stream), 2 edges/block
    edge_kernel<<<(E + 1) / 2, 256, 0, stream>>>(in_feat, query, skw, dkw, skb, dkb,
                                                 svw, dvw, svb, dvb, src, dst,
                                                 Kout, Vout, score, E);
    // B1: init (must run every call — ws not re-poisoned between replays)
    init_kernel<<<(ND + 255) / 256, 256, 0, stream>>>(smax, ssum, agg, NH, ND);
    // B2: segment max
    smax_kernel<<<(EH + 255) / 256, 256, 0, stream>>>(score, dst, smax, EH);
    // B3: exp + segment sum
    esum_kernel<<<(EH + 255) / 256, 256, 0, stream>>>(score, dst, smax, ex, ssum, EH);
    // B4: attn + scatter-sum into agg
    attn_agg_kernel<<<(ED + 255) / 256, 256, 0, stream>>>(ex, ssum, dst, Vout,
                                                          attn_out, agg, ED);
    // C: per-node linear + relu + residual + LayerNorm
    node_kernel<<<N, 256, 0, stream>>>(in_feat, node_w, node_b, agg,
                                       ln_g, ln_b, out_node, N);
}

// Round 4
// 182.624 us; speedup vs baseline: 1.1735x; 1.0328x over previous
//
#include <hip/hip_runtime.h>
#include <hip/hip_bf16.h>
#include <math.h>

// Problem constants (from reference): N=10000, E=50000, D=32, H=4, DH=8
#define DD 32
#define HH 4

__device__ __forceinline__ void atomicMaxFloat(float* addr, float val) {
    // sign-split trick; addr must be initialized to -inf
    if (val >= 0.0f) {
        atomicMax((int*)addr, __float_as_int(val));
    } else {
        atomicMin((unsigned int*)addr, __float_as_uint(val));
    }
}

// Async global->LDS stage of 1KB per wave-instruction: lane l moves 16B from
// g + l*16 to ldsbase + l*16 (HW: LDS dest is wave-uniform base + lane*size).
// No result VGPRs -> all staging loads stay in flight simultaneously.
__device__ __forceinline__ void stage1k(const float* __restrict__ g, float* l) {
    const int lane = threadIdx.x & 63;
    __builtin_amdgcn_global_load_lds(
        (const __attribute__((address_space(1))) void*)(g + lane * 4),
        (__attribute__((address_space(3))) void*)l,
        16, 0, 0);
}

// ---------------- Kernel A: per-edge linear + score -----------------
// One block (256 threads) per edge. tid = r*8 + t; r in [0,32): output row
// (= h*8+dh), t in [0,8): column quarter. Wave w stages rows 8w..8w+7 of all
// 4 weight arrays (4 x 1KB chunks) into its own LDS region via
// global_load_lds (no VGPR round-trip), so staging bandwidth is not limited
// by register-allocated load results. Each wave consumes only what it staged
// -> no barrier, just s_waitcnt vmcnt(0).
__global__ __launch_bounds__(256) void edge_kernel(
    const float* __restrict__ in_feat,  // [N,32]
    const float* __restrict__ query,    // [N,32]
    const float* __restrict__ skw, const float* __restrict__ dkw,
    const float* __restrict__ skb, const float* __restrict__ dkb,
    const float* __restrict__ svw, const float* __restrict__ dvw,
    const float* __restrict__ svb, const float* __restrict__ dvb,
    const int* __restrict__ src, const int* __restrict__ dst,
    float* __restrict__ Kout,   // [E,32] (d_out chunk 1)
    float* __restrict__ Vout,   // [E,32] (d_out chunk 2)
    float* __restrict__ score,  // [E,4]  (workspace)
    int E)
{
    __shared__ float lds[4096];  // 16KB: [wave][4 arrays][256 floats]

    const int tid  = threadIdx.x;
    const int lane = tid & 63;
    const int wv   = tid >> 6;   // 0..3
    const int r    = tid >> 3;   // 0..31
    const int t    = tid & 7;    // 0..7

    const int e = blockIdx.x;
    if (e >= E) return;

    const int s = src[e];
    const int d = dst[e];

    // ---- register loads (gathers + biases + query), issued up front ----
    const float4 u4 = *(const float4*)(in_feat + (size_t)s * DD + t * 4);
    const float4 v4 = *(const float4*)(in_feat + (size_t)d * DD + t * 4);
    const size_t bo = (size_t)e * DD + r;
    const float kb = skb[bo] + dkb[bo];
    const float vb = svb[bo] + dvb[bo];
    const float q  = query[(size_t)d * DD + r];

    // ---- async stage: wave w moves its 4KB (rows 8w..8w+7 of 4 arrays) ----
    const size_t gchunk = (size_t)e * 1024 + (size_t)wv * 256;  // float offset
    float* ldsw = &lds[wv * 1024];
    stage1k(skw + gchunk, ldsw + 0);
    stage1k(dkw + gchunk, ldsw + 256);
    stage1k(svw + gchunk, ldsw + 512);
    stage1k(dvw + gchunk, ldsw + 768);

    // wait for our wave's staging (and our register loads); no barrier needed
    asm volatile("s_waitcnt vmcnt(0)" ::: "memory");

    // ---- consume from LDS: lane reads back its own 16B slots ----
    const int li = lane * 4;
    const float4 a = *(const float4*)(ldsw + 0   + li);
    const float4 b = *(const float4*)(ldsw + 256 + li);
    const float4 c = *(const float4*)(ldsw + 512 + li);
    const float4 g = *(const float4*)(ldsw + 768 + li);

    float pk = a.x * u4.x + a.y * u4.y + a.z * u4.z + a.w * u4.w
             + b.x * v4.x + b.y * v4.y + b.z * v4.z + b.w * v4.w;
    float pv = c.x * u4.x + c.y * u4.y + c.z * u4.z + c.w * u4.w
             + g.x * v4.x + g.y * v4.y + g.z * v4.z + g.w * v4.w;

    // reduce over the 8 column-lanes
    #pragma unroll
    for (int m = 1; m <= 4; m <<= 1) {
        pk += __shfl_xor(pk, m);
        pv += __shfl_xor(pv, m);
    }

    const float kval = pk + kb;
    const float vval = pv + vb;
    if (t == 0) {
        Kout[bo] = kval;
        Vout[bo] = vval;
    }

    // head score: wave w holds rows 8w..8w+7 (head w); combine the 8
    // r-groups within the wave (masks 8/16/32 join lanes of equal t).
    float prod = kval * q;
    #pragma unroll
    for (int m = 8; m <= 32; m <<= 1) prod += __shfl_xor(prod, m);
    if (lane == 0) {
        score[(size_t)e * HH + wv] = prod;
    }
}

// ---------------- Kernel B1: init workspace ----------------
__global__ void init_kernel(float* __restrict__ smax, float* __restrict__ ssum,
                            float* __restrict__ agg, int NH, int ND)
{
    const int i = blockIdx.x * blockDim.x + threadIdx.x;
    if (i < NH) {
        smax[i] = __int_as_float(0xff800000);  // -inf
        ssum[i] = 0.0f;
    }
    if (i < ND) agg[i] = 0.0f;
}

// ---------------- Kernel B2: segment max ----------------
__global__ void smax_kernel(const float* __restrict__ score,
                            const int* __restrict__ dst,
                            float* __restrict__ smax, int EH)
{
    const int i = blockIdx.x * blockDim.x + threadIdx.x;
    if (i >= EH) return;
    const int e = i >> 2, h = i & 3;
    atomicMaxFloat(&smax[(size_t)dst[e] * HH + h], score[i]);
}

// ---------------- Kernel B3: exp + segment sum ----------------
__global__ void esum_kernel(const float* __restrict__ score,
                            const int* __restrict__ dst,
                            const float* __restrict__ smax,
                            float* __restrict__ ex, float* __restrict__ ssum,
                            int EH)
{
    const int i = blockIdx.x * blockDim.x + threadIdx.x;
    if (i >= EH) return;
    const int e = i >> 2, h = i & 3;
    const int d = dst[e];
    const float x = expf(score[i] - smax[(size_t)d * HH + h]);
    ex[i] = x;
    atomicAdd(&ssum[(size_t)d * HH + h], x);
}

// ---------------- Kernel B4: attn + weighted scatter-sum ----------------
__global__ void attn_agg_kernel(const float* __restrict__ ex,
                                const float* __restrict__ ssum,
                                const int* __restrict__ dst,
                                const float* __restrict__ V,     // [E,32]
                                float* __restrict__ attn_out,    // [E,4]
                                float* __restrict__ agg,         // [N,32]
                                int ED)
{
    const int i = blockIdx.x * blockDim.x + threadIdx.x;
    if (i >= ED) return;
    const int e = i >> 5, c = i & 31, h = c >> 3;
    const int d = dst[e];
    const float a = ex[(size_t)e * HH + h] / ssum[(size_t)d * HH + h];
    if ((c & 7) == 0) attn_out[(size_t)e * HH + h] = a;
    atomicAdd(&agg[(size_t)d * DD + c], V[i] * a);
}

// ---------------- Kernel C: node linear + relu + residual + LN ----------------
__global__ __launch_bounds__(256) void node_kernel(
    const float* __restrict__ in_feat,  // [N,32]
    const float* __restrict__ node_w,   // [N,32,32]
    const float* __restrict__ node_b,   // [N,32]
    const float* __restrict__ agg,      // [N,32]
    const float* __restrict__ ln_g, const float* __restrict__ ln_b,
    float* __restrict__ out, int N)
{
    __shared__ float ys[DD];
    const int n = blockIdx.x;
    if (n >= N) return;
    const int tid = threadIdx.x;
    const int r = tid >> 3, t = tid & 7;

    const float4 a4 = *(const float4*)(agg + (size_t)n * DD + t * 4);
    const float4 w4 = *(const float4*)(node_w + (size_t)n * 1024 + (size_t)r * 32 + t * 4);
    float p = w4.x * a4.x + w4.y * a4.y + w4.z * a4.z + w4.w * a4.w;
    #pragma unroll
    for (int m = 1; m <= 4; m <<= 1) p += __shfl_xor(p, m);
    if (t == 0) {
        float y = p + node_b[(size_t)n * DD + r];
        y = fmaxf(y, 0.0f) + in_feat[(size_t)n * DD + r];
        ys[r] = y;
    }
    __syncthreads();
    if (tid < 64) {
        const float y = (tid < DD) ? ys[tid] : 0.0f;
        float sum = y;
        #pragma unroll
        for (int m = 1; m <= 32; m <<= 1) sum += __shfl_xor(sum, m);
        const float mu = sum * (1.0f / DD);
        const float dy = (tid < DD) ? (y - mu) : 0.0f;
        float s2 = dy * dy;
        #pragma unroll
        for (int m = 1; m <= 32; m <<= 1) s2 += __shfl_xor(s2, m);
        const float var = s2 * (1.0f / DD);
        if (tid < DD) {
            out[(size_t)n * DD + tid] =
                dy * rsqrtf(var + 1e-5f) * ln_g[tid] + ln_b[tid];
        }
    }
}

extern "C" void kernel_launch(void* const* d_in, const int* in_sizes, int n_in,
                              void* d_out, int out_size, void* d_ws, size_t ws_size,
                              hipStream_t stream) {
    const float* in_feat = (const float*)d_in[0];
    const float* query   = (const float*)d_in[1];
    const float* skw     = (const float*)d_in[2];
    const float* dkw     = (const float*)d_in[3];
    const float* skb     = (const float*)d_in[4];
    const float* dkb     = (const float*)d_in[5];
    const float* svw     = (const float*)d_in[6];
    const float* dvw     = (const float*)d_in[7];
    const float* svb     = (const float*)d_in[8];
    const float* dvb     = (const float*)d_in[9];
    const float* node_w  = (const float*)d_in[10];
    const float* node_b  = (const float*)d_in[11];
    const float* ln_g    = (const float*)d_in[12];
    const float* ln_b    = (const float*)d_in[13];
    const int*   src     = (const int*)d_in[14];
    const int*   dst     = (const int*)d_in[15];

    const int N = in_sizes[0] / DD;     // 10000
    const int E = in_sizes[14];         // 50000
    const int NH = N * HH, ND = N * DD;
    const int EH = E * HH, ED = E * DD;

    // d_out layout (return order): out[N,32], K[E,32], V[E,32], attn[E,4]
    float* out_node = (float*)d_out;
    float* Kout     = out_node + (size_t)N * DD;
    float* Vout     = Kout + (size_t)E * DD;
    float* attn_out = Vout + (size_t)E * DD;

    // workspace: score[E*4] | ex[E*4] | smax[N*4] | ssum[N*4] | agg[N*32]
    float* ws    = (float*)d_ws;
    float* score = ws;
    float* ex    = score + EH;
    float* smax  = ex + EH;
    float* ssum  = smax + NH;
    float* agg   = ssum + NH;

    // A: per-edge linears + scores (dominant HBM stream), LDS-staged weights
    edge_kernel<<<E, 256, 0, stream>>>(in_feat, query, skw, dkw, skb, dkb,
                                       svw, dvw, svb, dvb, src, dst,
                                       Kout, Vout, score, E);
    // B1: init (must run every call — ws not re-poisoned between replays)
    init_kernel<<<(ND + 255) / 256, 256, 0, stream>>>(smax, ssum, agg, NH, ND);
    // B2: segment max
    smax_kernel<<<(EH + 255) / 256, 256, 0, stream>>>(score, dst, smax, EH);
    // B3: exp + segment sum
    esum_kernel<<<(EH + 255) / 256, 256, 0, stream>>>(score, dst, smax, ex, ssum, EH);
    // B4: attn + scatter-sum into agg
    attn_agg_kernel<<<(ED + 255) / 256, 256, 0, stream>>>(ex, ssum, dst, Vout,
                                                          attn_out, agg, ED);
    // C: per-node linear + relu + residual + LayerNorm
    node_kernel<<<N, 256, 0, stream>>>(in_feat, node_w, node_b, agg,
                                       ln_g, ln_b, out_node, N);
}